// Round 12
// baseline (63.562 us; speedup 1.0000x reference)
//
#include <hip/hip_runtime.h>
#include <math.h>

static constexpr int Bn = 32768;

// ws layout (floats)
#define WS_COEF  0        // [64][28] : per n {w, qc[3], cb[24]}  (cb idx = k*3+j)
#define WS_G     1792     // [8][8]
#define WS_g     1856     // [8]
#define WS_BW    1864     // [24]  b_w[k*3+m]
#define WS_Q00   1888
#define WS_WSUM  1889
#define WS_BATCH 1920     // [130][Bn] : 0..54 Qsym(upper), 55..126 FG[k*9+e], 127..129 y_w
#define WS_LMIN  (1920 + 130*Bn)   // [Bn]

__host__ __device__ constexpr int tidx(int i, int j) { return i*10 - i*(i+1)/2 + j; } // i<=j (upper packed, 10x10)
__host__ __device__ constexpr int tmm(int i, int j)  { return (i<j) ? tidx(i,j) : tidx(j,i); }
__host__ __device__ constexpr int lidx(int i, int j) { return i*(i+1)/2 + j; }        // i>=j (lower packed)
__host__ __device__ constexpr int lodx(int i, int j) { return i*(i-1)/2 + j; }        // i>j (strict lower packed)

// ---------------- K1: precompute (1 block, 64 threads; GJ parallelized in LDS) ----------------
__global__ void k_pre(const float* __restrict__ bb, const float* __restrict__ w,
                      const float* __restrict__ lam, float* __restrict__ ws)
{
  __shared__ float s_w[64], s_sw[64], s_bw[24], s_barb[64][24];
  __shared__ float s_BtB[64];
  __shared__ float s_M[8][16];      // [A | Iv]
  __shared__ float s_u[8], s_g[8], s_red[64], s_wsum, s_s;
  const int t = threadIdx.x;
  const int i8 = t >> 3, j8 = t & 7;
  const float lv = lam[0];

  s_w[t]  = w[t];
  s_sw[t] = sqrtf(fmaxf(s_w[t], 0.0f));
  __syncthreads();
  if (t == 0) { float a = 0; for (int n = 0; n < 64; n++) a += s_w[n]; s_wsum = a; }
  __syncthreads();
  const float wsum = s_wsum;
  if (t < 24) {                       // b_w[k*3+m]
    float a = 0;
    for (int n = 0; n < 64; n++) a += bb[t*64 + n] * s_w[n];
    s_bw[t] = a / wsum;
  }
  __syncthreads();
  for (int km = 0; km < 24; ++km)     // bar_b[n][km], t = n
    s_barb[t][km] = s_sw[t] * (bb[km*64 + t] - s_bw[km]);
  __syncthreads();
  {                                    // BtB, t = k*8+k2
    float a = 0;
    for (int n = 0; n < 64; n++)
      for (int j = 0; j < 3; j++)
        a += s_barb[n][i8*3 + j] * s_barb[n][j8*3 + j];
    s_BtB[t] = a;
  }
  __syncthreads();
  // ---- parallel Gauss-Jordan on [A | I], thread t owns (i8, j8) and (i8, 8+j8) ----
  s_M[i8][j8]     = 2.0f * (s_BtB[t] + ((i8 == j8) ? lv : 0.0f));
  s_M[i8][8 + j8] = (i8 == j8) ? 1.0f : 0.0f;
#pragma unroll
  for (int k = 0; k < 8; k++) {
    __syncthreads();
    const float fk  = s_M[i8][k];
    const float piv = 1.0f / s_M[k][k];
    __syncthreads();
    if (i8 == k) { s_M[k][j8] *= piv; s_M[k][8 + j8] *= piv; }
    __syncthreads();
    if (i8 != k) {
      s_M[i8][j8]     -= fk * s_M[k][j8];
      s_M[i8][8 + j8] -= fk * s_M[k][8 + j8];
    }
  }
  __syncthreads();
  if (t < 8) {
    float a = 0;
#pragma unroll
    for (int j = 0; j < 8; j++) a += s_M[t][8 + j];
    s_u[t] = a;
  }
  __syncthreads();
  if (t == 0) {
    float s = 0;
#pragma unroll
    for (int j = 0; j < 8; j++) s += s_u[j];
    s_s = s;
  }
  __syncthreads();
  const float s = s_s;
  if (t < 8) s_g[t] = s_u[t] / s;
  const float Gel = s_M[i8][8 + j8] - s_u[i8] * s_u[j8] / s;
  ws[WS_G + t] = Gel;
  __syncthreads();
  s_red[t] = s_g[i8] * (s_BtB[t] + ((i8 == j8) ? lv : 0.0f)) * s_g[j8];
  __syncthreads();
  if (t == 0) {
    float a = 0;
    for (int n = 0; n < 64; n++) a += s_red[n];
    ws[WS_Q00]  = a;
    ws[WS_WSUM] = wsum;
  }
  if (t < 8)  ws[WS_g + t]  = s_g[t];
  if (t < 24) ws[WS_BW + t] = s_bw[t];
  {                                     // packed per-n coefficients, t = n
    float* c = ws + WS_COEF + t*28;
    c[0] = s_w[t];
    float qc[3] = {0, 0, 0};
#pragma unroll
    for (int km = 0; km < 24; km++) {
      float cb = s_sw[t] * s_barb[t][km];
      c[4 + km] = cb;
      qc[km % 3] += s_g[km / 3] * cb;
    }
    c[1] = qc[0]; c[2] = qc[1]; c[3] = qc[2];
  }
}

// ---------------- K2: Q build, 4 thr/batch, y staged via coalesced LDS ----------------
__global__ __launch_bounds__(256, 1) void k_build(const float* __restrict__ y, float* __restrict__ ws)
{
  __shared__ float s_coef[64*28];   // [n][28]
  __shared__ float s_G[64], s_g[8];
  __shared__ float s_y[64*196];     // 64 batches x 192 floats, row stride 196 (2-way banks)
  __shared__ float s_F[72][66];     // [(k*3+j)*3+m][local batch], padded
  const int t   = threadIdx.x;
  const int lb  = t >> 2;           // local batch 0..63
  const int sub = t & 3;            // k-quarter: owns k in {2*sub, 2*sub+1}
  const int b   = blockIdx.x * 64 + lb;

  {                                  // coalesced stage: 64*192 floats, stride-1
    const float* ysrc = y + (size_t)blockIdx.x * 64 * 192;
    for (int i = t; i < 64*192; i += 256)
      s_y[(i/192)*196 + (i%192)] = ysrc[i];
  }
  for (int i = t; i < 64*28; i += 256) s_coef[i] = ws[WS_COEF + i];
  if (t < 64) s_G[t] = ws[WS_G + t];
  if (t < 8)  s_g[t] = ws[WS_g + t];
  __syncthreads();

  const float4* yrow = reinterpret_cast<const float4*>(s_y) + lb*49;   // 196/4 = 49
  const int kj0 = sub * 6;
  float F6[6][3];                   // my 6 kj rows of F
  float gw[6];
  float ywa[3] = {0, 0, 0};
#pragma unroll
  for (int i = 0; i < 6; i++) { F6[i][0] = 0; F6[i][1] = 0; F6[i][2] = 0; gw[i] = 0; }

  for (int n4 = 0; n4 < 16; n4++) {
    float4 v0 = yrow[n4];
    float4 v1 = yrow[16 + n4];
    float4 v2 = yrow[32 + n4];
    float a0[4] = {v0.x, v0.y, v0.z, v0.w};
    float a1[4] = {v1.x, v1.y, v1.z, v1.w};
    float a2[4] = {v2.x, v2.y, v2.z, v2.w};
#pragma unroll
    for (int l = 0; l < 4; l++) {
      const int n = 4*n4 + l;
      const float* c = s_coef + n*28;
      float ym0 = a0[l], ym1 = a1[l], ym2 = a2[l];
      float wn  = c[0];
      float wy0 = wn*ym0, wy1 = wn*ym1, wy2 = wn*ym2;
      ywa[0] += wy0; ywa[1] += wy1; ywa[2] += wy2;     // redundant across subs (cheap)
      gw[0] += wy0*ym0; gw[1] += wy0*ym1; gw[2] += wy0*ym2;
      gw[3] += wy1*ym1; gw[4] += wy1*ym2; gw[5] += wy2*ym2;
#pragma unroll
      for (int kk = 0; kk < 6; kk++) {
        float cb = c[4 + kj0 + kk];
        F6[kk][0] += cb*ym0; F6[kk][1] += cb*ym1; F6[kk][2] += cb*ym2;
      }
    }
  }

  float* wb = ws + WS_BATCH;
  const float wsum = ws[WS_WSUM];
  const float iws  = 1.0f / wsum;
  if (sub == 0) {
    wb[(size_t)(127 + 0)*Bn + b] = ywa[0]*iws;
    wb[(size_t)(127 + 1)*Bn + b] = ywa[1]*iws;
    wb[(size_t)(127 + 2)*Bn + b] = ywa[2]*iws;
  }
  if (sub == 1) wb[(size_t)tidx(0,0)*Bn + b] = ws[WS_Q00];
  float Gram[6];
  Gram[0] = gw[0] - ywa[0]*ywa[0]*iws;
  Gram[1] = gw[1] - ywa[0]*ywa[1]*iws;
  Gram[2] = gw[2] - ywa[0]*ywa[2]*iws;
  Gram[3] = gw[3] - ywa[1]*ywa[1]*iws;
  Gram[4] = gw[4] - ywa[1]*ywa[2]*iws;
  Gram[5] = gw[5] - ywa[2]*ywa[2]*iws;

  // stage my F rows for the cross-k FG sums
#pragma unroll
  for (int kk = 0; kk < 6; kk++)
#pragma unroll
    for (int m = 0; m < 3; m++)
      s_F[(kj0 + kk)*3 + m][lb] = F6[kk][m];

  // q_top: partial over my k's, butterfly, distributed writes (all lanes hold sum)
  {
    const float g0 = s_g[sub*2], g1 = s_g[sub*2 + 1];
#pragma unroll
    for (int e = 0; e < 9; e++) {
      const int j = e / 3, m = e % 3;
      float p = g0 * F6[j][m] + g1 * F6[3 + j][m];
      p += __shfl_xor(p, 1);
      p += __shfl_xor(p, 2);
      if ((e & 3) == sub) wb[(size_t)tidx(0, 1 + e)*Bn + b] = -p;
    }
  }
  __syncthreads();

  // FG rows for my k2 in {2*sub, 2*sub+1}: full-k sum from s_F
  float FGr[2][9];
#pragma unroll
  for (int kk = 0; kk < 2; kk++) {
    const int k2 = sub*2 + kk;
    float gcol[8];
#pragma unroll
    for (int k = 0; k < 8; k++) gcol[k] = s_G[k*8 + k2];
#pragma unroll
    for (int e = 0; e < 9; e++) {
      const int j = e / 3, m = e % 3;
      float a = 0;
#pragma unroll
      for (int k = 0; k < 8; k++) a += gcol[k] * s_F[(k*3 + j)*3 + m][lb];
      FGr[kk][e] = a;
      wb[(size_t)(55 + k2*9 + e)*Bn + b] = a;
    }
  }

  // q_low: per-sub partial (own regs only), butterfly, distributed writes
#pragma unroll
  for (int e = 0; e < 9; e++)
#pragma unroll
    for (int f = e; f < 9; f++) {
      const int j = e/3, m = e%3, j2 = f/3, m2 = f%3;
      float p = FGr[0][e] * F6[j2][m2] + FGr[1][e] * F6[3 + j2][m2];
      p += __shfl_xor(p, 1);
      p += __shfl_xor(p, 2);
      if ((tidx(1 + e, 1 + f) & 3) == sub) {
        const float gterm = (j == j2) ? Gram[(m <= m2) ? (m*3 - m*(m+1)/2 + m2) : (m2*3 - m2*(m2+1)/2 + m)] : 0.0f;
        wb[(size_t)tidx(1 + e, 1 + f)*Bn + b] = -2.0f*p + gterm;
      }
    }
}

// ---------------- K3a: lmin via Sturm bisection (LDLT inertia count) ----------------
__global__ __launch_bounds__(64, 1) void k_jac(const float* __restrict__ ws,
                                               float* __restrict__ ws_out)
{
  const int b = blockIdx.x * 64 + threadIdx.x;
  const float* wb = ws + WS_BATCH;
  float A[55];
#pragma unroll
  for (int i = 0; i < 55; i++) A[i] = wb[(size_t)i*Bn + b];

  float hi = A[tidx(0,0)];
#pragma unroll
  for (int j = 1; j < 10; j++) hi = fminf(hi, A[tidx(j,j)]);
  float lo = 0.0f;

  for (int it = 0; it < 22; ++it) {
    const float mid = 0.5f * (lo + hi);
    float L[45];
    float d[10];
    int neg = 0;
#pragma unroll
    for (int j = 0; j < 10; j++) {
      float dj = A[tidx(j,j)] - mid;
#pragma unroll
      for (int k = 0; k < j; k++) dj -= L[lodx(j,k)] * L[lodx(j,k)] * d[k];
      dj = (fabsf(dj) < 1e-30f) ? -1e-30f : dj;
      d[j] = dj;
      neg += (dj < 0.0f) ? 1 : 0;
      float inv = __builtin_amdgcn_rcpf(dj);
#pragma unroll
      for (int i2 = j + 1; i2 < 10; i2++) {
        float s = A[tmm(i2,j)];
#pragma unroll
        for (int k = 0; k < j; k++) s -= L[lodx(i2,k)] * L[lodx(j,k)] * d[k];
        L[lodx(i2,j)] = s * inv;
      }
    }
    if (neg == 0) lo = mid; else hi = mid;
  }
  ws_out[WS_LMIN + b] = lo;
}

// ---------------- K3b: Cholesky inverse iteration + outputs ----------------
__global__ __launch_bounds__(64, 1) void k_vec(const float* __restrict__ ws,
                                               float* __restrict__ out)
{
  const int b = blockIdx.x * 64 + threadIdx.x;
  const float* wb = ws + WS_BATCH;
  const float lmin = ws[WS_LMIN + b];

  float M[55];
  float id[10];
#pragma unroll
  for (int i = 0; i < 10; i++)
#pragma unroll
    for (int j = 0; j <= i; j++)
      M[lidx(i,j)] = wb[(size_t)tidx(j,i)*Bn + b];
  float tr = 0.0f;
#pragma unroll
  for (int i = 0; i < 10; i++) tr += M[lidx(i,i)];

  const float delta = 1e-5f * fabsf(tr) + 1e-30f;
  const float sigma = lmin - delta;
#pragma unroll
  for (int i = 0; i < 10; i++) M[lidx(i,i)] -= sigma;

#pragma unroll
  for (int j = 0; j < 10; j++) {
    float d = M[lidx(j,j)];
#pragma unroll
    for (int t2 = 0; t2 < j; t2++) d -= M[lidx(j,t2)] * M[lidx(j,t2)];
    d = fmaxf(d, 1e-30f);
    float is = __builtin_amdgcn_rsqf(d);
    id[j] = is;
#pragma unroll
    for (int i = j + 1; i < 10; i++) {
      float a = M[lidx(i,j)];
#pragma unroll
      for (int t2 = 0; t2 < j; t2++) a -= M[lidx(i,t2)] * M[lidx(j,t2)];
      M[lidx(i,j)] = a * is;
    }
  }

  float x[10];
#pragma unroll
  for (int i = 0; i < 10; i++) x[i] = 1.0f;

#pragma unroll
  for (int it = 0; it < 3; ++it) {
#pragma unroll
    for (int i = 0; i < 10; i++) {
      float a = x[i];
#pragma unroll
      for (int j = 0; j < i; j++) a -= M[lidx(i,j)] * x[j];
      x[i] = a * id[i];
    }
#pragma unroll
    for (int i = 9; i >= 0; i--) {
      float a = x[i];
#pragma unroll
      for (int j = i + 1; j < 10; j++) a -= M[lidx(j,i)] * x[j];
      x[i] = a * id[i];
    }
    float s2 = 0;
#pragma unroll
    for (int i = 0; i < 10; i++) s2 += x[i]*x[i];
    float sc = __builtin_amdgcn_rsqf(s2 + 1e-38f);
#pragma unroll
    for (int i = 0; i < 10; i++) x[i] *= sc;
  }

  const float inv0 = __builtin_amdgcn_rcpf(x[0]);
  float R[3][3];
#pragma unroll
  for (int r = 0; r < 3; r++)
#pragma unroll
    for (int cc = 0; cc < 3; cc++)
      R[r][cc] = x[1 + 3*cc + r] * inv0;
  float cvec[8];
#pragma unroll
  for (int k = 0; k < 8; k++) {
    float a = 0;
#pragma unroll
    for (int e = 0; e < 9; e++) a += x[1 + e] * wb[(size_t)(55 + k*9 + e)*Bn + b];
    cvec[k] = 2.0f * inv0 * a + ws[WS_g + k];
  }
  float um[3] = {0, 0, 0};
#pragma unroll
  for (int k = 0; k < 8; k++) {
    float ck = cvec[k];
    um[0] += ws[WS_BW + k*3 + 0] * ck;
    um[1] += ws[WS_BW + k*3 + 1] * ck;
    um[2] += ws[WS_BW + k*3 + 2] * ck;
  }
#pragma unroll
  for (int r = 0; r < 3; r++)
#pragma unroll
    for (int cc = 0; cc < 3; cc++)
      out[(size_t)b*9 + r*3 + cc] = R[r][cc];
#pragma unroll
  for (int r = 0; r < 3; r++) {
    float yw = wb[(size_t)(127 + r)*Bn + b];
    out[(size_t)9*Bn + b*3 + r] = yw - (R[r][0]*um[0] + R[r][1]*um[1] + R[r][2]*um[2]);
  }
#pragma unroll
  for (int k = 0; k < 8; k++)
    out[(size_t)12*Bn + b*8 + k] = cvec[k];
}

extern "C" void kernel_launch(void* const* d_in, const int* in_sizes, int n_in,
                              void* d_out, int out_size, void* d_ws, size_t ws_size,
                              hipStream_t stream) {
  const float* y   = (const float*)d_in[0];
  const float* bb  = (const float*)d_in[1];
  const float* w   = (const float*)d_in[2];
  const float* lam = (const float*)d_in[3];
  float* ws  = (float*)d_ws;
  float* out = (float*)d_out;
  k_pre  <<<1,       64, 0, stream>>>(bb, w, lam, ws);
  k_build<<<Bn/64,  256, 0, stream>>>(y, ws);
  k_jac  <<<Bn/64,   64, 0, stream>>>(ws, ws);
  k_vec  <<<Bn/64,   64, 0, stream>>>(ws, out);
}

// Round 13
// 51.061 us; speedup vs baseline: 1.2448x; 1.2448x over previous
//
#include <hip/hip_runtime.h>
#include <math.h>

static constexpr int Bn = 32768;

// ws layout (floats) — only the small precompute tables are used now
#define WS_COEF  0        // [64][28] : per n {w, qc[3], cb[24]}  (cb idx = k*3+j)
#define WS_G     1792     // [8][8]
#define WS_g     1856     // [8]
#define WS_BW    1864     // [24]  b_w[k*3+m]
#define WS_Q00   1888
#define WS_WSUM  1889

__host__ __device__ constexpr int tidx(int i, int j) { return i*10 - i*(i+1)/2 + j; } // i<=j (upper packed, 10x10)
__host__ __device__ constexpr int tmm(int i, int j)  { return (i<j) ? tidx(i,j) : tidx(j,i); }
__host__ __device__ constexpr int lidx(int i, int j) { return i*(i+1)/2 + j; }        // i>=j (lower packed)
__host__ __device__ constexpr int lodx(int i, int j) { return i*(i-1)/2 + j; }        // i>j (strict lower packed)

// ---------------- K1: precompute (1 block, 64 threads; GJ parallelized in LDS) ----------------
__global__ void k_pre(const float* __restrict__ bb, const float* __restrict__ w,
                      const float* __restrict__ lam, float* __restrict__ ws)
{
  __shared__ float s_w[64], s_sw[64], s_bw[24], s_barb[64][24];
  __shared__ float s_BtB[64];
  __shared__ float s_M[8][16];      // [A | Iv]
  __shared__ float s_u[8], s_g[8], s_red[64], s_wsum, s_s;
  const int t = threadIdx.x;
  const int i8 = t >> 3, j8 = t & 7;
  const float lv = lam[0];

  s_w[t]  = w[t];
  s_sw[t] = sqrtf(fmaxf(s_w[t], 0.0f));
  __syncthreads();
  if (t == 0) { float a = 0; for (int n = 0; n < 64; n++) a += s_w[n]; s_wsum = a; }
  __syncthreads();
  const float wsum = s_wsum;
  if (t < 24) {                       // b_w[k*3+m]
    float a = 0;
    for (int n = 0; n < 64; n++) a += bb[t*64 + n] * s_w[n];
    s_bw[t] = a / wsum;
  }
  __syncthreads();
  for (int km = 0; km < 24; ++km)     // bar_b[n][km], t = n
    s_barb[t][km] = s_sw[t] * (bb[km*64 + t] - s_bw[km]);
  __syncthreads();
  {                                    // BtB, t = k*8+k2
    float a = 0;
    for (int n = 0; n < 64; n++)
      for (int j = 0; j < 3; j++)
        a += s_barb[n][i8*3 + j] * s_barb[n][j8*3 + j];
    s_BtB[t] = a;
  }
  __syncthreads();
  // ---- parallel Gauss-Jordan on [A | I], thread t owns (i8, j8) and (i8, 8+j8) ----
  s_M[i8][j8]     = 2.0f * (s_BtB[t] + ((i8 == j8) ? lv : 0.0f));
  s_M[i8][8 + j8] = (i8 == j8) ? 1.0f : 0.0f;
#pragma unroll
  for (int k = 0; k < 8; k++) {
    __syncthreads();
    const float fk  = s_M[i8][k];
    const float piv = 1.0f / s_M[k][k];
    __syncthreads();
    if (i8 == k) { s_M[k][j8] *= piv; s_M[k][8 + j8] *= piv; }
    __syncthreads();
    if (i8 != k) {
      s_M[i8][j8]     -= fk * s_M[k][j8];
      s_M[i8][8 + j8] -= fk * s_M[k][8 + j8];
    }
  }
  __syncthreads();
  if (t < 8) {
    float a = 0;
#pragma unroll
    for (int j = 0; j < 8; j++) a += s_M[t][8 + j];
    s_u[t] = a;
  }
  __syncthreads();
  if (t == 0) {
    float s = 0;
#pragma unroll
    for (int j = 0; j < 8; j++) s += s_u[j];
    s_s = s;
  }
  __syncthreads();
  const float s = s_s;
  if (t < 8) s_g[t] = s_u[t] / s;
  const float Gel = s_M[i8][8 + j8] - s_u[i8] * s_u[j8] / s;
  ws[WS_G + t] = Gel;
  __syncthreads();
  s_red[t] = s_g[i8] * (s_BtB[t] + ((i8 == j8) ? lv : 0.0f)) * s_g[j8];
  __syncthreads();
  if (t == 0) {
    float a = 0;
    for (int n = 0; n < 64; n++) a += s_red[n];
    ws[WS_Q00]  = a;
    ws[WS_WSUM] = wsum;
  }
  if (t < 8)  ws[WS_g + t]  = s_g[t];
  if (t < 24) ws[WS_BW + t] = s_bw[t];
  {                                     // packed per-n coefficients, t = n
    float* c = ws + WS_COEF + t*28;
    c[0] = s_w[t];
    float qc[3] = {0, 0, 0};
#pragma unroll
    for (int km = 0; km < 24; km++) {
      float cb = s_sw[t] * s_barb[t][km];
      c[4 + km] = cb;
      qc[km % 3] += s_g[km / 3] * cb;
    }
    c[1] = qc[0]; c[2] = qc[1]; c[3] = qc[2];
  }
}

// ---------------- K2: fused build + quaternary-Sturm + Cholesky inverse-iteration ----------------
// 256 threads = 64 batches x 4 subs. Q lives in LDS; FG lives in per-sub regs; no ws round-trip.
__global__ __launch_bounds__(256, 1) void k_main(const float* __restrict__ y,
                                                 const float* __restrict__ ws,
                                                 float* __restrict__ out)
{
  __shared__ float s_coef[64*28];   // [n][28]
  __shared__ float s_G[64], s_g8[8], s_bw[24];
  __shared__ float s_F[72][66];     // [(k*3+j)*3+m][lb]
  __shared__ float s_Q[55][66];     // [packed upper idx][lb]
  const int t   = threadIdx.x;
  const int lb  = t >> 2;           // local batch 0..63
  const int sub = t & 3;            // k-quarter: owns k in {2*sub, 2*sub+1}
  const int b   = blockIdx.x * 64 + lb;

  for (int i = t; i < 64*28; i += 256) s_coef[i] = ws[WS_COEF + i];
  if (t < 64) s_G[t]  = ws[WS_G + t];
  if (t < 8)  s_g8[t] = ws[WS_g + t];
  if (t >= 8 && t < 32) s_bw[t - 8] = ws[WS_BW + (t - 8)];
  const float q00v = ws[WS_Q00];
  const float wsum = ws[WS_WSUM];
  __syncthreads();

  // ---- build phase (round-11 proven pattern, direct global y loads) ----
  const float* yb = y + (size_t)b * 192;
  const int kj0 = sub * 6;
  float F6[6][3];
  float gw[6];
  float ywa[3] = {0, 0, 0};
#pragma unroll
  for (int i = 0; i < 6; i++) { F6[i][0] = 0; F6[i][1] = 0; F6[i][2] = 0; gw[i] = 0; }

  for (int n4 = 0; n4 < 16; n4++) {
    float4 v0 = reinterpret_cast<const float4*>(yb)[n4];
    float4 v1 = reinterpret_cast<const float4*>(yb + 64)[n4];
    float4 v2 = reinterpret_cast<const float4*>(yb + 128)[n4];
    float a0[4] = {v0.x, v0.y, v0.z, v0.w};
    float a1[4] = {v1.x, v1.y, v1.z, v1.w};
    float a2[4] = {v2.x, v2.y, v2.z, v2.w};
#pragma unroll
    for (int l = 0; l < 4; l++) {
      const int n = 4*n4 + l;
      const float* c = s_coef + n*28;
      float ym0 = a0[l], ym1 = a1[l], ym2 = a2[l];
      float wn  = c[0];
      float wy0 = wn*ym0, wy1 = wn*ym1, wy2 = wn*ym2;
      ywa[0] += wy0; ywa[1] += wy1; ywa[2] += wy2;
      gw[0] += wy0*ym0; gw[1] += wy0*ym1; gw[2] += wy0*ym2;
      gw[3] += wy1*ym1; gw[4] += wy1*ym2; gw[5] += wy2*ym2;
#pragma unroll
      for (int kk = 0; kk < 6; kk++) {
        float cb = c[4 + kj0 + kk];
        F6[kk][0] += cb*ym0; F6[kk][1] += cb*ym1; F6[kk][2] += cb*ym2;
      }
    }
  }
  const float iws = 1.0f / wsum;
  float yw[3] = {ywa[0]*iws, ywa[1]*iws, ywa[2]*iws};
  float Gram[6];
  Gram[0] = gw[0] - ywa[0]*ywa[0]*iws;
  Gram[1] = gw[1] - ywa[0]*ywa[1]*iws;
  Gram[2] = gw[2] - ywa[0]*ywa[2]*iws;
  Gram[3] = gw[3] - ywa[1]*ywa[1]*iws;
  Gram[4] = gw[4] - ywa[1]*ywa[2]*iws;
  Gram[5] = gw[5] - ywa[2]*ywa[2]*iws;

  // stage F rows; q00 + q_top into s_Q
#pragma unroll
  for (int kk = 0; kk < 6; kk++)
#pragma unroll
    for (int m = 0; m < 3; m++)
      s_F[(kj0 + kk)*3 + m][lb] = F6[kk][m];
  if (sub == 0) s_Q[0][lb] = q00v;
  {
    const float g0 = s_g8[sub*2], g1 = s_g8[sub*2 + 1];
#pragma unroll
    for (int e = 0; e < 9; e++) {
      const int j = e / 3, m = e % 3;
      float p = g0 * F6[j][m] + g1 * F6[3 + j][m];
      p += __shfl_xor(p, 1);
      p += __shfl_xor(p, 2);
      if ((e & 3) == sub) s_Q[tidx(0, 1 + e)][lb] = -p;
    }
  }
  __syncthreads();

  // FG rows for my k2 in {2*sub, 2*sub+1} (kept in regs for the epilogue)
  float FGr[2][9];
#pragma unroll
  for (int kk = 0; kk < 2; kk++) {
    const int k2 = sub*2 + kk;
    float gcol[8];
#pragma unroll
    for (int k = 0; k < 8; k++) gcol[k] = s_G[k*8 + k2];
#pragma unroll
    for (int e = 0; e < 9; e++) {
      const int j = e / 3, m = e % 3;
      float a = 0;
#pragma unroll
      for (int k = 0; k < 8; k++) a += gcol[k] * s_F[(k*3 + j)*3 + m][lb];
      FGr[kk][e] = a;
    }
  }
  // q_low into s_Q (per-sub partial from own regs, butterfly, distributed writes)
#pragma unroll
  for (int e = 0; e < 9; e++)
#pragma unroll
    for (int f = e; f < 9; f++) {
      const int j = e/3, m = e%3, j2 = f/3, m2 = f%3;
      float p = FGr[0][e] * F6[j2][m2] + FGr[1][e] * F6[3 + j2][m2];
      p += __shfl_xor(p, 1);
      p += __shfl_xor(p, 2);
      if ((tidx(1 + e, 1 + f) & 3) == sub) {
        const float gterm = (j == j2) ? Gram[(m <= m2) ? (m*3 - m*(m+1)/2 + m2) : (m2*3 - m2*(m2+1)/2 + m)] : 0.0f;
        s_Q[tidx(1 + e, 1 + f)][lb] = -2.0f*p + gterm;
      }
    }
  __syncthreads();

  // ---- phase A: quaternary Sturm search (2 bits/round, 11 rounds == 22 binary) ----
  float lo = 0.0f, hi = s_Q[0][lb];
#pragma unroll
  for (int j = 1; j < 10; j++) hi = fminf(hi, s_Q[tidx(j,j)][lb]);

  const float subf = (sub == 0) ? 2.0f : (float)sub;
  for (int round = 0; round < 11; ++round) {
    const float quart = 0.25f * (hi - lo);
    const float mid = lo + quart * subf;
    float L[45], d[10];
    int neg = 0;
#pragma unroll
    for (int j = 0; j < 10; j++) {
      float dj = s_Q[tidx(j,j)][lb] - mid;
#pragma unroll
      for (int k = 0; k < j; k++) dj -= L[lodx(j,k)] * L[lodx(j,k)] * d[k];
      dj = (fabsf(dj) < 1e-30f) ? -1e-30f : dj;
      d[j] = dj;
      neg += (dj < 0.0f) ? 1 : 0;
      float inv = __builtin_amdgcn_rcpf(dj);
#pragma unroll
      for (int i2 = j + 1; i2 < 10; i2++) {
        float s2 = s_Q[tmm(i2,j)][lb];
#pragma unroll
        for (int k = 0; k < j; k++) s2 -= L[lodx(i2,k)] * L[lodx(j,k)] * d[k];
        L[lodx(i2,j)] = s2 * inv;
      }
    }
    const int base = t & ~3;
    const int n1 = __shfl(neg, base | 1);
    const int n2 = __shfl(neg, base | 2);
    const int n3 = __shfl(neg, base | 3);
    const float m1 = lo + quart, m2v = lo + 2.0f*quart, m3 = lo + 3.0f*quart;
    const float nlo = (n3 == 0) ? m3 : (n2 == 0) ? m2v : (n1 == 0) ? m1 : lo;
    const float nhi = (n1 > 0) ? m1 : (n2 > 0) ? m2v : (n3 > 0) ? m3 : hi;
    lo = nlo; hi = nhi;
  }

  // ---- phase B: Cholesky of (Q - sigma I) + 3 inverse iterations (all lanes, redundant x4) ----
  float M[55], id[10];
#pragma unroll
  for (int i = 0; i < 10; i++)
#pragma unroll
    for (int j = 0; j <= i; j++)
      M[lidx(i,j)] = s_Q[tidx(j,i)][lb];
  float tr = 0.0f;
#pragma unroll
  for (int i = 0; i < 10; i++) tr += M[lidx(i,i)];
  const float delta = 1e-5f * fabsf(tr) + 1e-30f;   // proven round-2 margin
  const float sigma = lo - delta;
#pragma unroll
  for (int i = 0; i < 10; i++) M[lidx(i,i)] -= sigma;

#pragma unroll
  for (int j = 0; j < 10; j++) {
    float d = M[lidx(j,j)];
#pragma unroll
    for (int t2 = 0; t2 < j; t2++) d -= M[lidx(j,t2)] * M[lidx(j,t2)];
    d = fmaxf(d, 1e-30f);
    float is = __builtin_amdgcn_rsqf(d);
    id[j] = is;
#pragma unroll
    for (int i = j + 1; i < 10; i++) {
      float a = M[lidx(i,j)];
#pragma unroll
      for (int t2 = 0; t2 < j; t2++) a -= M[lidx(i,t2)] * M[lidx(j,t2)];
      M[lidx(i,j)] = a * is;
    }
  }

  float x[10];
#pragma unroll
  for (int i = 0; i < 10; i++) x[i] = 1.0f;
#pragma unroll
  for (int it = 0; it < 3; ++it) {
#pragma unroll
    for (int i = 0; i < 10; i++) {
      float a = x[i];
#pragma unroll
      for (int j = 0; j < i; j++) a -= M[lidx(i,j)] * x[j];
      x[i] = a * id[i];
    }
#pragma unroll
    for (int i = 9; i >= 0; i--) {
      float a = x[i];
#pragma unroll
      for (int j = i + 1; j < 10; j++) a -= M[lidx(j,i)] * x[j];
      x[i] = a * id[i];
    }
    float s2 = 0;
#pragma unroll
    for (int i = 0; i < 10; i++) s2 += x[i]*x[i];
    float sc = __builtin_amdgcn_rsqf(s2 + 1e-38f);
#pragma unroll
    for (int i = 0; i < 10; i++) x[i] *= sc;
  }

  // ---- epilogue: R, c (per-sub pair from FGr), t ----
  const float inv0 = __builtin_amdgcn_rcpf(x[0]);
  float R[3][3];
#pragma unroll
  for (int r = 0; r < 3; r++)
#pragma unroll
    for (int cc = 0; cc < 3; cc++)
      R[r][cc] = x[1 + 3*cc + r] * inv0;

  float cv[2];
#pragma unroll
  for (int kk = 0; kk < 2; kk++) {
    const int k = sub*2 + kk;
    float a = 0;
#pragma unroll
    for (int e = 0; e < 9; e++) a += x[1 + e] * FGr[kk][e];
    cv[kk] = 2.0f * inv0 * a + s_g8[k];
    out[(size_t)12*Bn + (size_t)b*8 + k] = cv[kk];
  }
  float um0 = s_bw[(sub*2)*3 + 0]*cv[0] + s_bw[(sub*2 + 1)*3 + 0]*cv[1];
  float um1 = s_bw[(sub*2)*3 + 1]*cv[0] + s_bw[(sub*2 + 1)*3 + 1]*cv[1];
  float um2 = s_bw[(sub*2)*3 + 2]*cv[0] + s_bw[(sub*2 + 1)*3 + 2]*cv[1];
  um0 += __shfl_xor(um0, 1); um0 += __shfl_xor(um0, 2);
  um1 += __shfl_xor(um1, 1); um1 += __shfl_xor(um1, 2);
  um2 += __shfl_xor(um2, 1); um2 += __shfl_xor(um2, 2);

#pragma unroll
  for (int r = 0; r < 3; r++)
#pragma unroll
    for (int cc = 0; cc < 3; cc++)
      if (((r*3 + cc) & 3) == sub)
        out[(size_t)b*9 + r*3 + cc] = R[r][cc];
  if (sub == 0) {
#pragma unroll
    for (int r = 0; r < 3; r++)
      out[(size_t)9*Bn + (size_t)b*3 + r] = yw[r] - (R[r][0]*um0 + R[r][1]*um1 + R[r][2]*um2);
  }
}

extern "C" void kernel_launch(void* const* d_in, const int* in_sizes, int n_in,
                              void* d_out, int out_size, void* d_ws, size_t ws_size,
                              hipStream_t stream) {
  const float* y   = (const float*)d_in[0];
  const float* bb  = (const float*)d_in[1];
  const float* w   = (const float*)d_in[2];
  const float* lam = (const float*)d_in[3];
  float* ws  = (float*)d_ws;
  float* out = (float*)d_out;
  k_pre <<<1,      64, 0, stream>>>(bb, w, lam, ws);
  k_main<<<Bn/64, 256, 0, stream>>>(y, ws, out);
}